// Round 5
// baseline (123.015 us; speedup 1.0000x reference)
//
#include <hip/hip_runtime.h>
#include <hip/hip_fp16.h>

// NCC loss: 9^3 box sums of {I, J, I*I, J*J, I*J}, per-voxel cc, -mean(cc).
// Dims: C=2, D=192, H=224, W=192, fp32. Separable box filter:
//   K1 (k_hwsum): BARRIER-FREE. wave = one d-slice row strip, 64 lanes x 3 px
//                 = W=192. H-sum via I/J register ring (products recomputed on
//                 subtract), W-sum via wave-private LDS row + s_waitcnt only
//                 (same-wave LDS is ordered; no __syncthreads in the loop).
//                 -> fp16 2D sums.
//   K2 (k_dsum):  D-sum — barrier-free streaming register ring + cc + reduce.

#define C2   2
#define DDIM 192
#define HDIM 224
#define WDIM 192
#define HWN  (HDIM*WDIM)              // 43008
#define VOL  ((size_t)DDIM*HWN)       // 8257536
#define RAD  4
#define WINV (1.0f/729.0f)

#define HT1  28     // K1 h-strip per wave (224/28 = 8 strips)
#define NROW 204    // LDS row floats: [0..3]=left pad, 4+w (w<192), [196..203]=right pad

// ---------------- K1: H-sum + W-sum of 5 product fields, 1 wave/row ----------------
// grid: ((nd+3)/4, HDIM/HT1, C2); block: 256 = 4 waves = 4 consecutive d-slices
// buf layout (fp16): [f][c][bd][h][w], bd = d - d0 + 4, fstride = C2*bufD*HWN
__global__ __launch_bounds__(256, 3)
void k_hwsum(const float* __restrict__ I, const float* __restrict__ J,
             __half* __restrict__ buf, int d0, int dbeg, int dend, int bufD)
{
    const int tid = threadIdx.x;
    const int wv  = tid >> 6;         // wave within block
    const int l   = tid & 63;         // lane
    const int w0  = 3 * l;            // first of 3 owned pixels
    int d = dbeg + 4*blockIdx.x + wv;
    if (d >= dend) d = dend - 1;      // duplicate wave: writes identical data
    const int h0 = blockIdx.y * HT1;
    const int c  = blockIdx.z;

    __shared__ float wrow[4][5][NROW];    // wave-private rows, 16.3 KB

    // zero the W-halo pads of this wave's rows (wave-local, no barrier needed)
    if (l < 4) {
        #pragma unroll
        for (int f = 0; f < 5; ++f) wrow[wv][f][l] = 0.f;
    }
    if (l < 8) {
        #pragma unroll
        for (int f = 0; f < 5; ++f) wrow[wv][f][196 + l] = 0.f;
    }

    const float* Ib = I + (size_t)c*VOL + (size_t)d*HWN + w0;
    const float* Jb = J + (size_t)c*VOL + (size_t)d*HWN + w0;

    float3 ringI[9], ringJ[9];
    float3 rs[5];
    #pragma unroll
    for (int f = 0; f < 5; ++f) { rs[f].x = 0.f; rs[f].y = 0.f; rs[f].z = 0.f; }

    // warm-up: ring slots 0..7 = I,J rows h0-4 .. h0+3 (zero padded)
    #pragma unroll
    for (int k = 0; k < 8; ++k) {
        const int h = h0 - RAD + k;
        float3 iv = {0.f,0.f,0.f}, jv = {0.f,0.f,0.f};
        if (h >= 0 && h < HDIM) {
            iv = *(const float3*)(Ib + (size_t)h*WDIM);
            jv = *(const float3*)(Jb + (size_t)h*WDIM);
        }
        ringI[k] = iv; ringJ[k] = jv;
        rs[0].x += iv.x;      rs[0].y += iv.y;      rs[0].z += iv.z;
        rs[1].x += jv.x;      rs[1].y += jv.y;      rs[1].z += jv.z;
        rs[2].x += iv.x*iv.x; rs[2].y += iv.y*iv.y; rs[2].z += iv.z*iv.z;
        rs[3].x += jv.x*jv.x; rs[3].y += jv.y*jv.y; rs[3].z += jv.z*jv.z;
        rs[4].x += iv.x*jv.x; rs[4].y += iv.y*jv.y; rs[4].z += iv.z*jv.z;
    }

    // one-step prefetch of row h0+4
    float3 niv = {0.f,0.f,0.f}, njv = {0.f,0.f,0.f};
    {
        const int hf = h0 + RAD;
        if (hf < HDIM) {
            niv = *(const float3*)(Ib + (size_t)hf*WDIM);
            njv = *(const float3*)(Jb + (size_t)hf*WDIM);
        }
    }

    const size_t fstride = (size_t)C2*bufD*HWN;
    __half* ob = buf + ((size_t)c*bufD + (size_t)(d - d0 + RAD))*HWN + w0;
    float* const rowp = &wrow[wv][0][0];   // field f at rowp + f*NROW

    int i = 0;
    while (i < HT1) {
        #pragma unroll
        for (int p9 = 0; p9 < 9; ++p9) {   // i == p9 (mod 9) whenever body runs
            if (i < HT1) {
                const int h = h0 + i;
                const float3 iv = niv, jv = njv;
                // prefetch next step's row
                niv.x=0.f; niv.y=0.f; niv.z=0.f; njv.x=0.f; njv.y=0.f; njv.z=0.f;
                const int hf2 = h + 1 + RAD;
                if (i + 1 < HT1 && hf2 < HDIM) {
                    niv = *(const float3*)(Ib + (size_t)hf2*WDIM);
                    njv = *(const float3*)(Jb + (size_t)hf2*WDIM);
                }
                // H-ring add of row h+4 products; write H-sums (rows h-4..h+4)
                rs[0].x += iv.x;      rs[0].y += iv.y;      rs[0].z += iv.z;
                rs[1].x += jv.x;      rs[1].y += jv.y;      rs[1].z += jv.z;
                rs[2].x += iv.x*iv.x; rs[2].y += iv.y*iv.y; rs[2].z += iv.z*iv.z;
                rs[3].x += jv.x*jv.x; rs[3].y += jv.y*jv.y; rs[3].z += jv.z*jv.z;
                rs[4].x += iv.x*jv.x; rs[4].y += iv.y*jv.y; rs[4].z += iv.z*jv.z;
                #pragma unroll
                for (int f = 0; f < 5; ++f) {
                    float* q = rowp + f*NROW + 4 + w0;
                    q[0] = rs[f].x; q[1] = rs[f].y; q[2] = rs[f].z;
                }
                // drop row h-4 (recompute its products from I/J ring)
                {
                    const float3 ri = ringI[p9], rj = ringJ[p9];
                    rs[0].x -= ri.x;      rs[0].y -= ri.y;      rs[0].z -= ri.z;
                    rs[1].x -= rj.x;      rs[1].y -= rj.y;      rs[1].z -= rj.z;
                    rs[2].x -= ri.x*ri.x; rs[2].y -= ri.y*ri.y; rs[2].z -= ri.z*ri.z;
                    rs[3].x -= rj.x*rj.x; rs[3].y -= rj.y*rj.y; rs[3].z -= rj.z*rj.z;
                    rs[4].x -= ri.x*rj.x; rs[4].y -= ri.y*rj.y; rs[4].z -= ri.z*rj.z;
                    ringI[(p9+8)%9] = iv; ringJ[(p9+8)%9] = jv;   // keep row h+4
                }
                // wave-synchronous: drain own LDS writes, then read taps.
                asm volatile("s_waitcnt lgkmcnt(0)" ::: "memory");
                #pragma unroll
                for (int f = 0; f < 5; ++f) {
                    const float* q = rowp + f*NROW + 3*l;   // idx 3l .. 3l+10
                    const float a0=q[0], a1=q[1], a2=q[2], a3=q[3], a4=q[4];
                    const float a5=q[5], a6=q[6], a7=q[7], a8=q[8], a9=q[9], a10=q[10];
                    const float o0 = ((a0+a1)+(a2+a3)) + ((a4+a5)+(a6+a7)) + a8;
                    const float o1 = o0 - a0 + a9;
                    const float o2 = o1 - a1 + a10;
                    __half* pf = ob + f*fstride + (size_t)h*WDIM;
                    *reinterpret_cast<__half2*>(pf) = __floats2half2_rn(o0, o1);
                    pf[2] = __float2half_rn(o2);
                }
                ++i;
            }
        }
    }
}

// -------- K2: D-sum (register ring) + cc + block reduce — no LDS, no syncs --------
// grid: (HWN/256, nsub, C2); block: 256 threads
__global__ __launch_bounds__(256)
void k_dsum(const __half* __restrict__ buf, double* __restrict__ gacc,
            int d0, int bufD, int DS)
{
    const int tid = threadIdx.x;
    const int pix = blockIdx.x*256 + tid;     // (h,w) flat, HWN = 168*256 exact
    const int c   = blockIdx.z;
    const int ds0 = d0 + blockIdx.y*DS;

    const size_t fstride = (size_t)C2*bufD*HWN;
    const __half* base = buf + (size_t)c*bufD*HWN + pix;

    float ring[5][9];
    float rs[5] = {0.f,0.f,0.f,0.f,0.f};
    float acc = 0.f;

    // warm-up: slices ds0-4 .. ds0+3
    #pragma unroll
    for (int k = 0; k < 8; ++k) {
        const int dd = ds0 - RAD + k;
        float v[5] = {0.f,0.f,0.f,0.f,0.f};
        if ((unsigned)dd < (unsigned)DDIM) {
            const __half* pp = base + (size_t)(dd - d0 + RAD)*HWN;
            #pragma unroll
            for (int f = 0; f < 5; ++f) v[f] = __half2float(pp[(size_t)f*fstride]);
        }
        #pragma unroll
        for (int f = 0; f < 5; ++f) { ring[f][k] = v[f]; rs[f] += v[f]; }
    }

    int i = 0;
    while (i < DS) {
        #pragma unroll
        for (int p = 0; p < 9; ++p) {   // i == p (mod 9) whenever body runs
            if (i < DS) {
                const int dd = ds0 + i + RAD;
                float v[5] = {0.f,0.f,0.f,0.f,0.f};
                if (dd < DDIM) {
                    const __half* pp = base + (size_t)(dd - d0 + RAD)*HWN;
                    #pragma unroll
                    for (int f = 0; f < 5; ++f) v[f] = __half2float(pp[(size_t)f*fstride]);
                }
                float S[5];
                #pragma unroll
                for (int f = 0; f < 5; ++f) {
                    rs[f] += v[f];              // full 9x9x9 sum at dd-4
                    S[f] = rs[f];
                    rs[f] -= ring[f][p];        // drop slice dd-8
                    ring[f][(p+8)%9] = v[f];    // keep slice dd
                }
                const float uI    = S[0]*WINV;
                const float uJ    = S[1]*WINV;
                const float cross = S[4] - uJ*S[0];
                const float Iv    = S[2] - uI*S[0];
                const float Jv    = S[3] - uJ*S[1];
                acc += cross*cross / (Iv*Jv + 1e-5f);
                ++i;
            }
        }
    }

    // block reduction -> one double atomic per block
    __shared__ float wred[4];
    #pragma unroll
    for (int off = 32; off > 0; off >>= 1) acc += __shfl_down(acc, off);
    if ((tid & 63) == 0) wred[tid >> 6] = acc;
    __syncthreads();
    if (tid == 0) {
        const float sum = wred[0] + wred[1] + wred[2] + wred[3];
        atomicAdd(gacc, (double)sum);
    }
}

__global__ void k_fin(const double* __restrict__ gacc, float* __restrict__ out)
{
    out[0] = (float)(-gacc[0] / (double)((size_t)C2*DDIM*HDIM*WDIM));
}

extern "C" void kernel_launch(void* const* d_in, const int* in_sizes, int n_in,
                              void* d_out, int out_size, void* d_ws, size_t ws_size,
                              hipStream_t stream)
{
    if (n_in < 2) return;
    const float* I = (const float*)d_in[0];
    const float* J = (const float*)d_in[1];
    float* out = (float*)d_out;
    double* gacc = (double*)d_ws;
    __half* buf = (__half*)((char*)d_ws + 256);

    // choose D-chunk so the 5-field fp16 2D-summed buffer fits ws
    static const int cands[] = {192, 96, 48, 24, 12, 6, 4, 2, 1};
    int Dc = 0;
    for (int c : cands) {
        const size_t need = 256 + (size_t)5*C2*(c+8)*HWN*sizeof(__half);
        if (need <= ws_size) { Dc = c; break; }
    }
    if (Dc == 0) return;  // ws too small — cannot run

    hipMemsetAsync(d_ws, 0, 256, stream);   // zero the double accumulator

    const int DS   = (Dc % 48 == 0) ? 48 : Dc;  // K2 sub-chunk along D
    const int nsub = Dc / DS;
    const int bufD = Dc + 8;

    for (int d0 = 0; d0 < DDIM; d0 += Dc) {
        const int dbeg = (d0 - RAD < 0) ? 0 : d0 - RAD;
        const int dend = (d0 + Dc + RAD > DDIM) ? DDIM : d0 + Dc + RAD;
        const int nd   = dend - dbeg;
        dim3 g1((nd + 3)/4, HDIM/HT1, C2);
        k_hwsum<<<g1, dim3(256,1,1), 0, stream>>>(I, J, buf, d0, dbeg, dend, bufD);
        dim3 g2(HWN/256, nsub, C2);
        k_dsum<<<g2, dim3(256,1,1), 0, stream>>>(buf, gacc, d0, bufD, DS);
    }
    k_fin<<<1,1,0,stream>>>(gacc, out);
}